// Round 3
// baseline (533.517 us; speedup 1.0000x reference)
//
#include <hip/hip_runtime.h>
#include <hip/hip_bf16.h>
#include <stdint.h>

#define Bv 8
#define Sv 512
#define Hv 768
#define Iv 3072
#define Ev 7
#define Tv (Bv*Sv)        // 4096 tokens
#define ROWS (Tv*2)       // 8192 routed rows (top-2)

typedef __attribute__((ext_vector_type(8))) short short8;
typedef __attribute__((ext_vector_type(4))) float f32x4;

__device__ __forceinline__ unsigned short f2bf(float f) {
  union { float f; unsigned u; } v; v.f = f;
  unsigned u = v.u;
  return (unsigned short)((u + 0x7fffu + ((u >> 16) & 1u)) >> 16);  // RNE
}

// global -> LDS direct copy, 16B per lane. LDS dest must be linear:
// per-wave uniform base + lane*16 (we pass base + tid*16; HW takes firstlane).
__device__ __forceinline__ void gload16(const void* g, void* l) {
  __builtin_amdgcn_global_load_lds(
      (const __attribute__((address_space(1))) unsigned int*)(uintptr_t)g,
      (__attribute__((address_space(3))) unsigned int*)(unsigned int)(uintptr_t)l,
      16, 0, 0);
}

// ---------------------------------------------------------------- gate
// One wave per token: f64 gate logits (top-2 flip safety), top-2 softmax,
// dense gate_weights out, x -> bf16, route counts + per-token route info.
__global__ __launch_bounds__(256) void gate_kernel(
    const float* __restrict__ x, const float* __restrict__ gW,
    const float* __restrict__ gb, float* __restrict__ gw_out,
    unsigned short* __restrict__ xb, int* __restrict__ tok_e,
    float* __restrict__ tok_w, int* __restrict__ cnt)
{
  int t = blockIdx.x * 4 + (threadIdx.x >> 6);
  int lane = threadIdx.x & 63;
  const float* xr = x + (size_t)t * Hv;
  float xv[12];
  #pragma unroll
  for (int i = 0; i < 12; ++i) {
    float v = xr[lane + i * 64];
    xv[i] = v;
    xb[(size_t)t * Hv + lane + i * 64] = f2bf(v);
  }
  double lg[Ev];
  #pragma unroll
  for (int e = 0; e < Ev; ++e) {
    const float* we = gW + e * Hv;
    double s = 0.0;
    #pragma unroll
    for (int i = 0; i < 12; ++i) s += (double)xv[i] * (double)we[lane + i * 64];
    #pragma unroll
    for (int o = 32; o > 0; o >>= 1) s += __shfl_xor(s, o);
    lg[e] = s + (double)gb[e];
  }
  if (lane == 0) {
    int i0 = 0;
    #pragma unroll
    for (int e = 1; e < Ev; ++e) if (lg[e] > lg[i0]) i0 = e;   // strict >: lowest-index tie-break
    int i1 = (i0 == 0) ? 1 : 0;
    #pragma unroll
    for (int e = 0; e < Ev; ++e) if (e != i0 && e != i1 && lg[e] > lg[i1]) i1 = e;
    double d  = lg[i1] - lg[i0];            // <= 0
    double w0 = 1.0 / (1.0 + exp(d));
    double w1 = 1.0 - w0;
    gw_out[(size_t)t * Ev + i0] = (float)w0;
    gw_out[(size_t)t * Ev + i1] = (float)w1;
    tok_e[t * 2 + 0] = i0; tok_e[t * 2 + 1] = i1;
    tok_w[t * 2 + 0] = (float)w0; tok_w[t * 2 + 1] = (float)w1;
    atomicAdd(&cnt[i0], 1);
    atomicAdd(&cnt[i1], 1);
  }
}

__global__ void scan_kernel(const int* __restrict__ cnt, int* __restrict__ offs,
                            int* __restrict__ cur)
{
  if (threadIdx.x == 0) {
    int s = 0;
    for (int e = 0; e < Ev; ++e) { offs[e] = s; cur[e] = s; s += cnt[e]; }
  }
}

__global__ __launch_bounds__(256) void fill_kernel(
    const int* __restrict__ tok_e, const float* __restrict__ tok_w,
    int* __restrict__ cur, int* __restrict__ rowmap, float* __restrict__ roww)
{
  int t = blockIdx.x * 256 + threadIdx.x;
  #pragma unroll
  for (int k = 0; k < 2; ++k) {
    int e = tok_e[t * 2 + k];
    int pos = atomicAdd(&cur[e], 1);
    rowmap[pos] = t;
    roww[pos] = tok_w[t * 2 + k];
  }
}

// ---------------------------------------------------------------- W transpose+convert
// src f32 [E][R][C] -> dst bf16 [E][C][R]  (B^T layout for MFMA staging)
__global__ __launch_bounds__(256) void tconv_kernel(
    const float* __restrict__ src, unsigned short* __restrict__ dst, int R, int C)
{
  __shared__ float tile[32][33];
  int e = blockIdx.z;
  int c0 = blockIdx.x * 32, r0 = blockIdx.y * 32;
  int tx = threadIdx.x, ty = threadIdx.y;
  const float* s = src + (size_t)e * R * C;
  unsigned short* d = dst + (size_t)e * C * R;
  #pragma unroll
  for (int i = ty; i < 32; i += 8)
    tile[i][tx] = s[(size_t)(r0 + i) * C + c0 + tx];
  __syncthreads();
  #pragma unroll
  for (int i = ty; i < 32; i += 8)
    d[(size_t)(c0 + i) * R + r0 + tx] = f2bf(tile[tx][i]);
}

// ---------------------------------------------------------------- GEMM1 (routed)
// h[slot, 0..I) = gelu( x[rowmap[slot], :] @ W1[e] + b1[e] ), bf16 out.
// 128x128 tile, BK=32, 4 waves (2x2), 16x16x32 bf16 MFMA, dbuf LDS + global_load_lds.
__global__ __launch_bounds__(256, 2) void gemm1_kernel(
    const unsigned short* __restrict__ xb, const unsigned short* __restrict__ w1t,
    const float* __restrict__ b1, const int* __restrict__ rowmap,
    const int* __restrict__ offs, const int* __restrict__ cnt,
    unsigned short* __restrict__ hbuf)
{
  int e = blockIdx.z;
  int count = cnt[e];
  int mt = blockIdx.y;
  if (mt * 128 >= count) return;
  int nt = blockIdx.x;
  int base = offs[e];

  __shared__ unsigned short lA[2][128 * 32];
  __shared__ unsigned short lB[2][128 * 32];

  int tid = threadIdx.x;
  int lane = tid & 63;
  int wv = tid >> 6;
  int wm = wv >> 1, wn = wv & 1;

  int ra = tid >> 2;            // staging row 0..63
  int ca = (tid & 3) * 8;       // staging k-offset (ushorts)
  int s0 = min(base + mt * 128 + ra, ROWS - 1);
  int s1 = min(base + mt * 128 + ra + 64, ROWS - 1);
  int tok0 = rowmap[s0];
  int tok1 = rowmap[s1];
  const unsigned short* gA0 = xb + (size_t)tok0 * Hv + ca;
  const unsigned short* gA1 = xb + (size_t)tok1 * Hv + ca;
  const unsigned short* gB0 = w1t + ((size_t)e * Iv + nt * 128 + ra) * Hv + ca;
  const unsigned short* gB1 = gB0 + (size_t)64 * Hv;

  f32x4 acc[4][4] = {};
  int arow = lane & 15;
  int ko8 = (lane >> 4) * 8;

  gload16(gA0, &lA[0][tid * 8]);
  gload16(gA1, &lA[0][(256 + tid) * 8]);
  gload16(gB0, &lB[0][tid * 8]);
  gload16(gB1, &lB[0][(256 + tid) * 8]);
  __syncthreads();

  const int NKT = Hv / 32;  // 24
  for (int kt = 0; kt < NKT; ++kt) {
    int bi = kt & 1;
    if (kt + 1 < NKT) {
      int ko = (kt + 1) * 32;
      gload16(gA0 + ko, &lA[bi ^ 1][tid * 8]);
      gload16(gA1 + ko, &lA[bi ^ 1][(256 + tid) * 8]);
      gload16(gB0 + ko, &lB[bi ^ 1][tid * 8]);
      gload16(gB1 + ko, &lB[bi ^ 1][(256 + tid) * 8]);
    }
    short8 af[4], bf[4];
    #pragma unroll
    for (int i = 0; i < 4; ++i) {
      af[i] = *(const short8*)&lA[bi][(wm * 64 + i * 16 + arow) * 32 + ko8];
      bf[i] = *(const short8*)&lB[bi][(wn * 64 + i * 16 + arow) * 32 + ko8];
    }
    #pragma unroll
    for (int i = 0; i < 4; ++i)
      #pragma unroll
      for (int j = 0; j < 4; ++j)
        acc[i][j] = __builtin_amdgcn_mfma_f32_16x16x32_bf16(af[i], bf[j], acc[i][j], 0, 0, 0);
    __syncthreads();
  }

  int crow = (lane >> 4) * 4;
  int ccol = lane & 15;
  #pragma unroll
  for (int mi = 0; mi < 4; ++mi) {
    #pragma unroll
    for (int j = 0; j < 4; ++j) {
      int rloc = mt * 128 + wm * 64 + mi * 16 + crow + j;
      if (rloc < count) {
        size_t slot = (size_t)(base + rloc);
        #pragma unroll
        for (int nj = 0; nj < 4; ++nj) {
          int n = nt * 128 + wn * 64 + nj * 16 + ccol;
          float v = acc[mi][nj][j] + b1[e * Iv + n];
          float g = 0.5f * v * (1.0f + erff(v * 0.70710678118654752f));  // exact gelu
          hbuf[slot * Iv + n] = f2bf(g);
        }
      }
    }
  }
}

// ---------------------------------------------------------------- GEMM2 (routed, split-K=2)
// out[rowmap[slot], :] += w[slot] * ( h[slot,:] @ W2[e] + b2[e] )  via f32 atomics.
__global__ __launch_bounds__(256, 2) void gemm2_kernel(
    const unsigned short* __restrict__ hbuf, const unsigned short* __restrict__ w2t,
    const float* __restrict__ b2, const int* __restrict__ rowmap,
    const float* __restrict__ roww, const int* __restrict__ offs,
    const int* __restrict__ cnt, float* __restrict__ out)
{
  int z = blockIdx.z;
  int e = z >> 1, kz = z & 1;
  int count = cnt[e];
  int mt = blockIdx.y;
  if (mt * 128 >= count) return;
  int nt = blockIdx.x;
  int base = offs[e];

  __shared__ unsigned short lA[2][128 * 32];
  __shared__ unsigned short lB[2][128 * 32];

  int tid = threadIdx.x;
  int lane = tid & 63;
  int wv = tid >> 6;
  int wm = wv >> 1, wn = wv & 1;

  int ra = tid >> 2;
  int ca = (tid & 3) * 8;
  int s0 = min(base + mt * 128 + ra, ROWS - 1);
  int s1 = min(base + mt * 128 + ra + 64, ROWS - 1);
  const int K0 = kz * (Iv / 2);
  const unsigned short* gA0 = hbuf + (size_t)s0 * Iv + K0 + ca;
  const unsigned short* gA1 = hbuf + (size_t)s1 * Iv + K0 + ca;
  const unsigned short* gB0 = w2t + ((size_t)e * Hv + nt * 128 + ra) * Iv + K0 + ca;
  const unsigned short* gB1 = gB0 + (size_t)64 * Iv;

  f32x4 acc[4][4] = {};
  int arow = lane & 15;
  int ko8 = (lane >> 4) * 8;

  gload16(gA0, &lA[0][tid * 8]);
  gload16(gA1, &lA[0][(256 + tid) * 8]);
  gload16(gB0, &lB[0][tid * 8]);
  gload16(gB1, &lB[0][(256 + tid) * 8]);
  __syncthreads();

  const int NKT = (Iv / 2) / 32;  // 48
  for (int kt = 0; kt < NKT; ++kt) {
    int bi = kt & 1;
    if (kt + 1 < NKT) {
      int ko = (kt + 1) * 32;
      gload16(gA0 + ko, &lA[bi ^ 1][tid * 8]);
      gload16(gA1 + ko, &lA[bi ^ 1][(256 + tid) * 8]);
      gload16(gB0 + ko, &lB[bi ^ 1][tid * 8]);
      gload16(gB1 + ko, &lB[bi ^ 1][(256 + tid) * 8]);
    }
    short8 af[4], bf[4];
    #pragma unroll
    for (int i = 0; i < 4; ++i) {
      af[i] = *(const short8*)&lA[bi][(wm * 64 + i * 16 + arow) * 32 + ko8];
      bf[i] = *(const short8*)&lB[bi][(wn * 64 + i * 16 + arow) * 32 + ko8];
    }
    #pragma unroll
    for (int i = 0; i < 4; ++i)
      #pragma unroll
      for (int j = 0; j < 4; ++j)
        acc[i][j] = __builtin_amdgcn_mfma_f32_16x16x32_bf16(af[i], bf[j], acc[i][j], 0, 0, 0);
    __syncthreads();
  }

  int crow = (lane >> 4) * 4;
  int ccol = lane & 15;
  #pragma unroll
  for (int mi = 0; mi < 4; ++mi) {
    #pragma unroll
    for (int j = 0; j < 4; ++j) {
      int rloc = mt * 128 + wm * 64 + mi * 16 + crow + j;
      if (rloc < count) {
        int slot = base + rloc;
        int token = rowmap[slot];
        float w = roww[slot];
        float* orow = out + (size_t)token * Hv;
        #pragma unroll
        for (int nj = 0; nj < 4; ++nj) {
          int n = nt * 128 + wn * 64 + nj * 16 + ccol;
          float v = acc[mi][nj][j];
          if (kz == 0) v += b2[e * Hv + n];
          atomicAdd(&orow[n], w * v);
        }
      }
    }
  }
}

// ---------------------------------------------------------------- launch
extern "C" void kernel_launch(void* const* d_in, const int* in_sizes, int n_in,
                              void* d_out, int out_size, void* d_ws, size_t ws_size,
                              hipStream_t stream)
{
  (void)in_sizes; (void)n_in; (void)ws_size;
  const float* x  = (const float*)d_in[0];
  const float* gW = (const float*)d_in[1];
  const float* gb = (const float*)d_in[2];
  const float* W1 = (const float*)d_in[3];
  const float* b1 = (const float*)d_in[4];
  const float* W2 = (const float*)d_in[5];
  const float* b2 = (const float*)d_in[6];
  float* out = (float*)d_out;
  float* gw_out = out + (size_t)Tv * Hv;

  char* ws = (char*)d_ws;
  size_t off = 0;
  auto take = [&](size_t bytes) -> char* {
    char* p = ws + off;
    off = (off + bytes + 255) & ~(size_t)255;
    return p;
  };
  int*   cnt    = (int*)take(8 * 4);
  int*   offs   = (int*)take(8 * 4);
  int*   cur    = (int*)take(8 * 4);
  int*   tok_e  = (int*)take((size_t)Tv * 2 * 4);
  float* tok_w  = (float*)take((size_t)Tv * 2 * 4);
  int*   rowmap = (int*)take((size_t)ROWS * 4);
  float* roww   = (float*)take((size_t)ROWS * 4);
  unsigned short* xb   = (unsigned short*)take((size_t)Tv * Hv * 2);
  unsigned short* w1t  = (unsigned short*)take((size_t)Ev * Iv * Hv * 2);
  unsigned short* w2t  = (unsigned short*)take((size_t)Ev * Hv * Iv * 2);
  unsigned short* hbuf = (unsigned short*)take((size_t)ROWS * Iv * 2);
  // total ws: ~123 MB

  hipMemsetAsync(d_out, 0, (size_t)out_size * sizeof(float), stream);
  hipMemsetAsync(ws, 0, 768, stream);  // cnt/offs/cur control block

  gate_kernel<<<Tv / 4, 256, 0, stream>>>(x, gW, gb, gw_out, xb, tok_e, tok_w, cnt);
  scan_kernel<<<1, 64, 0, stream>>>(cnt, offs, cur);
  fill_kernel<<<Tv / 256, 256, 0, stream>>>(tok_e, tok_w, cur, rowmap, roww);
  tconv_kernel<<<dim3(Iv / 32, Hv / 32, Ev), dim3(32, 8), 0, stream>>>(W1, w1t, Hv, Iv);
  tconv_kernel<<<dim3(Hv / 32, Iv / 32, Ev), dim3(32, 8), 0, stream>>>(W2, w2t, Iv, Hv);
  gemm1_kernel<<<dim3(Iv / 128, 32, Ev), 256, 0, stream>>>(xb, w1t, b1, rowmap, offs, cnt, hbuf);
  gemm2_kernel<<<dim3(Hv / 128, 32, Ev * 2), 256, 0, stream>>>(hbuf, w2t, b2, rowmap, roww, offs, cnt, out);
}

// Round 5
// 509.652 us; speedup vs baseline: 1.0468x; 1.0468x over previous
//
#include <hip/hip_runtime.h>
#include <hip/hip_bf16.h>
#include <stdint.h>

#define Bv 8
#define Sv 512
#define Hv 768
#define Iv 3072
#define Ev 7
#define Tv (Bv*Sv)        // 4096 tokens
#define ROWS (Tv*2)       // 8192 routed rows (top-2)

typedef __attribute__((ext_vector_type(8))) short short8;
typedef __attribute__((ext_vector_type(4))) float f32x4;

__device__ __forceinline__ unsigned short f2bf(float f) {
  union { float f; unsigned u; } v; v.f = f;
  unsigned u = v.u;
  return (unsigned short)((u + 0x7fffu + ((u >> 16) & 1u)) >> 16);  // RNE
}

// global -> LDS direct copy, 16B per lane. LDS dest must be linear
// (wave-uniform base + lane*16); per-lane GLOBAL source may be arbitrary,
// which is how the LDS swizzle is applied (pre-swizzled source, rule 21).
__device__ __forceinline__ void gload16(const void* g, void* l) {
  __builtin_amdgcn_global_load_lds(
      (const __attribute__((address_space(1))) unsigned int*)(uintptr_t)g,
      (__attribute__((address_space(3))) unsigned int*)(unsigned int)(uintptr_t)l,
      16, 0, 0);
}

// ---------------------------------------------------------------- gate
__global__ __launch_bounds__(256) void gate_kernel(
    const float* __restrict__ x, const float* __restrict__ gW,
    const float* __restrict__ gb, float* __restrict__ gw_out,
    unsigned short* __restrict__ xb, int* __restrict__ tok_e,
    float* __restrict__ tok_w, int* __restrict__ cnt)
{
  int t = blockIdx.x * 4 + (threadIdx.x >> 6);
  int lane = threadIdx.x & 63;
  const float* xr = x + (size_t)t * Hv;
  float xv[12];
  #pragma unroll
  for (int i = 0; i < 12; ++i) {
    float v = xr[lane + i * 64];
    xv[i] = v;
    xb[(size_t)t * Hv + lane + i * 64] = f2bf(v);
  }
  double lg[Ev];
  #pragma unroll
  for (int e = 0; e < Ev; ++e) {
    const float* we = gW + e * Hv;
    double s = 0.0;
    #pragma unroll
    for (int i = 0; i < 12; ++i) s += (double)xv[i] * (double)we[lane + i * 64];
    #pragma unroll
    for (int o = 32; o > 0; o >>= 1) s += __shfl_xor(s, o);
    lg[e] = s + (double)gb[e];
  }
  if (lane == 0) {
    int i0 = 0;
    #pragma unroll
    for (int e = 1; e < Ev; ++e) if (lg[e] > lg[i0]) i0 = e;   // strict >: lowest-index tie-break
    int i1 = (i0 == 0) ? 1 : 0;
    #pragma unroll
    for (int e = 0; e < Ev; ++e) if (e != i0 && e != i1 && lg[e] > lg[i1]) i1 = e;
    double d  = lg[i1] - lg[i0];            // <= 0
    double w0 = 1.0 / (1.0 + exp(d));
    double w1 = 1.0 - w0;
    gw_out[(size_t)t * Ev + i0] = (float)w0;
    gw_out[(size_t)t * Ev + i1] = (float)w1;
    tok_e[t * 2 + 0] = i0; tok_e[t * 2 + 1] = i1;
    tok_w[t * 2 + 0] = (float)w0; tok_w[t * 2 + 1] = (float)w1;
    atomicAdd(&cnt[i0], 1);
    atomicAdd(&cnt[i1], 1);
  }
}

__global__ void scan_kernel(const int* __restrict__ cnt, int* __restrict__ offs,
                            int* __restrict__ cur)
{
  if (threadIdx.x == 0) {
    int s = 0;
    for (int e = 0; e < Ev; ++e) { offs[e] = s; cur[e] = s; s += cnt[e]; }
  }
}

__global__ __launch_bounds__(256) void fill_kernel(
    const int* __restrict__ tok_e, const float* __restrict__ tok_w,
    int* __restrict__ cur, int* __restrict__ rowmap, float* __restrict__ roww)
{
  int t = blockIdx.x * 256 + threadIdx.x;
  #pragma unroll
  for (int k = 0; k < 2; ++k) {
    int e = tok_e[t * 2 + k];
    int pos = atomicAdd(&cur[e], 1);
    rowmap[pos] = t;
    roww[pos] = tok_w[t * 2 + k];
  }
}

// ---------------------------------------------------------------- W transpose+convert
__global__ __launch_bounds__(256) void tconv_kernel(
    const float* __restrict__ src, unsigned short* __restrict__ dst, int R, int C)
{
  __shared__ float tile[32][33];
  int e = blockIdx.z;
  int c0 = blockIdx.x * 32, r0 = blockIdx.y * 32;
  int tx = threadIdx.x, ty = threadIdx.y;
  const float* s = src + (size_t)e * R * C;
  unsigned short* d = dst + (size_t)e * C * R;
  #pragma unroll
  for (int i = ty; i < 32; i += 8)
    tile[i][tx] = s[(size_t)(r0 + i) * C + c0 + tx];
  __syncthreads();
  #pragma unroll
  for (int i = ty; i < 32; i += 8)
    d[(size_t)(c0 + i) * R + r0 + tx] = f2bf(tile[tx][i]);
}

// ---------------------------------------------------------------- GEMM1 (routed)
// 256x256 tile, BK=32, 8 waves (2x4), 16x16x32 bf16 MFMA, dbuf LDS,
// global_load_lds w/ pre-swizzled source (slot ^= (row>>1)&3, 2-way-free banks).
__global__ __launch_bounds__(512, 2) void gemm1_kernel(
    const unsigned short* __restrict__ xb, const unsigned short* __restrict__ w1t,
    const float* __restrict__ b1, const int* __restrict__ rowmap,
    const int* __restrict__ offs, const int* __restrict__ cnt,
    unsigned short* __restrict__ hbuf)
{
  int e = blockIdx.z;
  int count = cnt[e];
  int mt = blockIdx.y;
  if (mt * 256 >= count) return;
  int nt = blockIdx.x;
  int base = offs[e];

  __shared__ unsigned short lA[2][256 * 32];
  __shared__ unsigned short lB[2][256 * 32];

  int tid = threadIdx.x;
  int lane = tid & 63;
  int wv = tid >> 6;
  int wm = wv >> 2, wn = wv & 3;        // wave grid 2(M) x 4(N)

  // staging: thread t covers tile-row (t>>2), 16B slot (t&3); source chunk
  // pre-swizzled so swizzled reads recover linear k-groups.
  int rowc = tid >> 2;                  // 0..127 (call covers 128 rows)
  int chunk = (tid & 3) ^ ((tid >> 3) & 3);
  int sA0 = min(base + mt * 256 + rowc, ROWS - 1);
  int sA1 = min(base + mt * 256 + 128 + rowc, ROWS - 1);
  const unsigned short* gA0 = xb + (size_t)rowmap[sA0] * Hv + chunk * 8;
  const unsigned short* gA1 = xb + (size_t)rowmap[sA1] * Hv + chunk * 8;
  const unsigned short* gB0 = w1t + ((size_t)e * Iv + nt * 256 + rowc) * Hv + chunk * 8;
  const unsigned short* gB1 = gB0 + (size_t)128 * Hv;

  f32x4 acc[8][4] = {};
  int fr = lane & 15;
  int sx = ((lane >> 4) ^ ((lane >> 1) & 3)) * 8;  // swizzled 16B-slot (ushort units)

  auto stage = [&](int buf, int k0) {
    gload16(gA0 + k0, &lA[buf][tid * 8]);
    gload16(gA1 + k0, &lA[buf][4096 + tid * 8]);
    gload16(gB0 + k0, &lB[buf][tid * 8]);
    gload16(gB1 + k0, &lB[buf][4096 + tid * 8]);
  };

  stage(0, 0);
  __syncthreads();

  const int NKT = Hv / 32;  // 24
  int cur = 0;
  for (int kt = 0; kt < NKT; ++kt) {
    if (kt + 1 < NKT) stage(cur ^ 1, (kt + 1) * 32);
    short8 af[8], bfr[4];
    #pragma unroll
    for (int i = 0; i < 8; ++i)
      af[i] = *(const short8*)&lA[cur][(wm * 128 + i * 16 + fr) * 32 + sx];
    #pragma unroll
    for (int j = 0; j < 4; ++j)
      bfr[j] = *(const short8*)&lB[cur][(wn * 64 + j * 16 + fr) * 32 + sx];
    #pragma unroll
    for (int i = 0; i < 8; ++i)
      #pragma unroll
      for (int j = 0; j < 4; ++j)
        acc[i][j] = __builtin_amdgcn_mfma_f32_16x16x32_bf16(af[i], bfr[j], acc[i][j], 0, 0, 0);
    __syncthreads();
    cur ^= 1;
  }

  int crow = (lane >> 4) * 4;
  int ccol = lane & 15;
  float bias[4];
  #pragma unroll
  for (int nj = 0; nj < 4; ++nj)
    bias[nj] = b1[e * Iv + nt * 256 + wn * 64 + nj * 16 + ccol];
  #pragma unroll
  for (int mi = 0; mi < 8; ++mi) {
    #pragma unroll
    for (int j = 0; j < 4; ++j) {
      int rloc = mt * 256 + wm * 128 + mi * 16 + crow + j;
      if (rloc < count) {
        size_t slot = (size_t)(base + rloc);
        #pragma unroll
        for (int nj = 0; nj < 4; ++nj) {
          int n = nt * 256 + wn * 64 + nj * 16 + ccol;
          float v = acc[mi][nj][j] + bias[nj];
          float g = 0.5f * v * (1.0f + erff(v * 0.70710678118654752f));  // exact gelu
          hbuf[slot * Iv + n] = f2bf(g);
        }
      }
    }
  }
}

// ---------------------------------------------------------------- GEMM2 (routed, split-K=2)
__global__ __launch_bounds__(512, 2) void gemm2_kernel(
    const unsigned short* __restrict__ hbuf, const unsigned short* __restrict__ w2t,
    const float* __restrict__ b2, const int* __restrict__ rowmap,
    const float* __restrict__ roww, const int* __restrict__ offs,
    const int* __restrict__ cnt, float* __restrict__ out)
{
  int z = blockIdx.z;
  int e = z >> 1, kz = z & 1;
  int count = cnt[e];
  int mt = blockIdx.y;
  if (mt * 256 >= count) return;
  int nt = blockIdx.x;
  int base = offs[e];

  __shared__ unsigned short lA[2][256 * 32];
  __shared__ unsigned short lB[2][256 * 32];

  int tid = threadIdx.x;
  int lane = tid & 63;
  int wv = tid >> 6;
  int wm = wv >> 2, wn = wv & 3;

  int rowc = tid >> 2;
  int chunk = (tid & 3) ^ ((tid >> 3) & 3);
  int sA0 = min(base + mt * 256 + rowc, ROWS - 1);
  int sA1 = min(base + mt * 256 + 128 + rowc, ROWS - 1);
  const int K0 = kz * (Iv / 2);
  const unsigned short* gA0 = hbuf + (size_t)sA0 * Iv + K0 + chunk * 8;
  const unsigned short* gA1 = hbuf + (size_t)sA1 * Iv + K0 + chunk * 8;
  const unsigned short* gB0 = w2t + ((size_t)e * Hv + nt * 256 + rowc) * Iv + K0 + chunk * 8;
  const unsigned short* gB1 = gB0 + (size_t)128 * Iv;

  f32x4 acc[8][4] = {};
  int fr = lane & 15;
  int sx = ((lane >> 4) ^ ((lane >> 1) & 3)) * 8;

  auto stage = [&](int buf, int k0) {
    gload16(gA0 + k0, &lA[buf][tid * 8]);
    gload16(gA1 + k0, &lA[buf][4096 + tid * 8]);
    gload16(gB0 + k0, &lB[buf][tid * 8]);
    gload16(gB1 + k0, &lB[buf][4096 + tid * 8]);
  };

  stage(0, 0);
  __syncthreads();

  const int NKT = (Iv / 2) / 32;  // 48
  int cur = 0;
  for (int kt = 0; kt < NKT; ++kt) {
    if (kt + 1 < NKT) stage(cur ^ 1, (kt + 1) * 32);
    short8 af[8], bfr[4];
    #pragma unroll
    for (int i = 0; i < 8; ++i)
      af[i] = *(const short8*)&lA[cur][(wm * 128 + i * 16 + fr) * 32 + sx];
    #pragma unroll
    for (int j = 0; j < 4; ++j)
      bfr[j] = *(const short8*)&lB[cur][(wn * 64 + j * 16 + fr) * 32 + sx];
    #pragma unroll
    for (int i = 0; i < 8; ++i)
      #pragma unroll
      for (int j = 0; j < 4; ++j)
        acc[i][j] = __builtin_amdgcn_mfma_f32_16x16x32_bf16(af[i], bfr[j], acc[i][j], 0, 0, 0);
    __syncthreads();
    cur ^= 1;
  }

  int crow = (lane >> 4) * 4;
  int ccol = lane & 15;
  float bias[4];
  #pragma unroll
  for (int nj = 0; nj < 4; ++nj)
    bias[nj] = (kz == 0) ? b2[e * Hv + nt * 256 + wn * 64 + nj * 16 + ccol] : 0.0f;
  #pragma unroll
  for (int mi = 0; mi < 8; ++mi) {
    #pragma unroll
    for (int j = 0; j < 4; ++j) {
      int rloc = mt * 256 + wm * 128 + mi * 16 + crow + j;
      if (rloc < count) {
        int slot = base + rloc;
        int token = rowmap[slot];
        float w = roww[slot];
        float* orow = out + (size_t)token * Hv;
        #pragma unroll
        for (int nj = 0; nj < 4; ++nj) {
          int n = nt * 256 + wn * 64 + nj * 16 + ccol;
          atomicAdd(&orow[n], w * (acc[mi][nj][j] + bias[nj]));
        }
      }
    }
  }
}

// ---------------------------------------------------------------- launch
extern "C" void kernel_launch(void* const* d_in, const int* in_sizes, int n_in,
                              void* d_out, int out_size, void* d_ws, size_t ws_size,
                              hipStream_t stream)
{
  (void)in_sizes; (void)n_in; (void)ws_size;
  const float* x  = (const float*)d_in[0];
  const float* gW = (const float*)d_in[1];
  const float* gb = (const float*)d_in[2];
  const float* W1 = (const float*)d_in[3];
  const float* b1 = (const float*)d_in[4];
  const float* W2 = (const float*)d_in[5];
  const float* b2 = (const float*)d_in[6];
  float* out = (float*)d_out;
  float* gw_out = out + (size_t)Tv * Hv;

  char* ws = (char*)d_ws;
  size_t off = 0;
  auto take = [&](size_t bytes) -> char* {
    char* p = ws + off;
    off = (off + bytes + 255) & ~(size_t)255;
    return p;
  };
  int*   cnt    = (int*)take(8 * 4);
  int*   offs   = (int*)take(8 * 4);
  int*   cur    = (int*)take(8 * 4);
  int*   tok_e  = (int*)take((size_t)Tv * 2 * 4);
  float* tok_w  = (float*)take((size_t)Tv * 2 * 4);
  int*   rowmap = (int*)take((size_t)ROWS * 4);
  float* roww   = (float*)take((size_t)ROWS * 4);
  unsigned short* xb   = (unsigned short*)take((size_t)Tv * Hv * 2);
  unsigned short* w1t  = (unsigned short*)take((size_t)Ev * Iv * Hv * 2);
  unsigned short* w2t  = (unsigned short*)take((size_t)Ev * Hv * Iv * 2);
  unsigned short* hbuf = (unsigned short*)take((size_t)ROWS * Iv * 2);
  // total ws: ~123 MB

  hipMemsetAsync(d_out, 0, (size_t)out_size * sizeof(float), stream);
  hipMemsetAsync(ws, 0, 768, stream);  // cnt/offs/cur control block

  gate_kernel<<<Tv / 4, 256, 0, stream>>>(x, gW, gb, gw_out, xb, tok_e, tok_w, cnt);
  scan_kernel<<<1, 64, 0, stream>>>(cnt, offs, cur);
  fill_kernel<<<Tv / 256, 256, 0, stream>>>(tok_e, tok_w, cur, rowmap, roww);
  tconv_kernel<<<dim3(Iv / 32, Hv / 32, Ev), dim3(32, 8), 0, stream>>>(W1, w1t, Hv, Iv);
  tconv_kernel<<<dim3(Hv / 32, Iv / 32, Ev), dim3(32, 8), 0, stream>>>(W2, w2t, Iv, Hv);
  gemm1_kernel<<<dim3(Iv / 256, 16, Ev), 512, 0, stream>>>(xb, w1t, b1, rowmap, offs, cnt, hbuf);
  gemm2_kernel<<<dim3(Hv / 256, 16, Ev * 2), 512, 0, stream>>>(hbuf, w2t, b2, rowmap, roww, offs, cnt, out);
}